// Round 16
// baseline (980.427 us; speedup 1.0000x reference)
//
#include <hip/hip_runtime.h>
#include <hip/hip_bf16.h>
#include <math.h>

typedef short bf16x8 __attribute__((ext_vector_type(8)));
typedef float f32x4 __attribute__((ext_vector_type(4)));

#define DEV __device__ __forceinline__

DEV ushort f2b(float x) {
    unsigned u = __float_as_uint(x);
    u += 0x7fffu + ((u >> 16) & 1u);
    return (ushort)(u >> 16);
}
DEV float b2f(ushort h) { return __uint_as_float(((unsigned)h) << 16); }
DEV float gelu_f(float x) { return 0.5f * x * (1.0f + erff(x * 0.70710678118654752f)); }

// async global->LDS, 16B per lane; LDS dest wave-uniform base (lane*16 added by HW)
DEV void gl2lds16(const void* g, void* l) {
    __builtin_amdgcn_global_load_lds(
        (const __attribute__((address_space(1))) void*)(uintptr_t)g,
        (__attribute__((address_space(3))) void*)(uintptr_t)l, 16, 0, 0);
}

#define BAR() __builtin_amdgcn_s_barrier()

// ---------------------------------------------------------------------------
// prep_k: data cast + ALL weight transposes + pw table in ONE launch.
// Blocks [0,25088): dcast; [25088,37888): weight casts; [37888,37890): pw.
// ---------------------------------------------------------------------------
DEV void cast1(const float* __restrict__ W, ushort* __restrict__ Wt, int K, int N, long i) {
    int k = (int)(i / N), n = (int)(i % N);
    Wt[(long)n * K + k] = f2b(W[i]);
}
__global__ __launch_bounds__(256) void prep_k(
    const float* __restrict__ data, ushort* __restrict__ dataB, int* __restrict__ pw,
    const float* s0, ushort* d0, const float* s1, ushort* d1, const float* s2, ushort* d2,
    const float* s3, ushort* d3, const float* s4, ushort* d4, const float* s5, ushort* d5,
    const float* s6, ushort* d6, const float* s7, ushort* d7) {
    int blk = blockIdx.x;
    if (blk < 25088) {
        // dcast: data[:, 2:1026] f32 -> bf16 [50176][1024]
        long i = ((long)blk * 256 + threadIdx.x) * 8;
        int r = (int)(i >> 10);
        int c = (int)(i & 1023);
        const float* p = data + (long)r * 1026 + 2 + c;
        float2 f0 = *(const float2*)p;
        float2 f1 = *(const float2*)(p + 2);
        float2 f2 = *(const float2*)(p + 4);
        float2 f3 = *(const float2*)(p + 6);
        int4 pk;
        pk.x = (int)f2b(f0.x) | ((int)f2b(f0.y) << 16);
        pk.y = (int)f2b(f1.x) | ((int)f2b(f1.y) << 16);
        pk.z = (int)f2b(f2.x) | ((int)f2b(f2.y) << 16);
        pk.w = (int)f2b(f3.x) | ((int)f2b(f3.y) << 16);
        *(int4*)(&dataB[i]) = pk;
    } else if (blk < 37888) {
        long i = (long)(blk - 25088) * 256 + threadIdx.x;
        if (i < 524288) cast1(s0, d0, 1024, 512, i);                  // fc1
        else if (i < 1310720) cast1(s1, d1, 512, 1536, i - 524288);   // wa qkv
        else if (i < 1572864) cast1(s2, d2, 512, 512, i - 1310720);   // wa proj
        else if (i < 2359296) cast1(s3, d3, 512, 1536, i - 1572864);  // sa qkv
        else if (i < 2621440) cast1(s4, d4, 512, 512, i - 2359296);   // sa proj
        else if (i < 2883584) cast1(s5, d5, 512, 512, i - 2621440);   // mlp1
        else if (i < 3145728) cast1(s6, d6, 512, 512, i - 2883584);   // mlp2
        else cast1(s7, d7, 512, 256, i - 3145728);                    // ap1
    } else {
        int d = (blk - 37888) * 256 + threadIdx.x;
        if (d < 512) {
            int v;
            if (d == 0) v = 0;
            else if (d <= 3) v = 1;
            else {
                float t = logf((float)d / 1.9f) / 1.7917594692280552f * 3.8f;
                int r = (int)rintf(t);
                v = r < 7 ? r : 7;
            }
            pw[d] = v;
        }
    }
}

// ---------------------------------------------------------------------------
// GEMM: C[M x N] = A[M x K] @ B[K x N] (+bias, epilogues). A bf16, out bf16.
// BM=BN=128, BK=32, 4 waves, 16x16x32 MFMA.
// FROZEN round-13 K-loop: 3-buffer A+B gl2lds16, single barrier, counted
// vmcnt(4) (prefetch distance 2). Schedule experiments closed (r5/7/13/14).
// LDS-staged coalesced epilogue (C tile -> LDS -> int4 flat writeback).
// EPI: 0 relu  1 plain  2 gelu(hres+x)  3 out[perm?] += x  4 gelu  5 tanh
//      6 ap1-fused: aPart[row*2 + (n0>>7)] = sum_col tanh(acc+bias)*w2[col]
//        (plain store: each row x n-half owned by exactly one lane)
// ---------------------------------------------------------------------------
template <int EPI, bool PERMA, bool PERMOUT>
__global__ __launch_bounds__(256, 3) void gemm_k(const ushort* __restrict__ A, long lda,
                                                 const ushort* __restrict__ Bt,
                                                 const float* __restrict__ bias,
                                                 const ushort* __restrict__ hresB,
                                                 ushort* __restrict__ outB,
                                                 const float* __restrict__ w2g,
                                                 float* __restrict__ aPart, int N, int K) {
    __shared__ ushort sh[3][2][128 * 32];  // 48 KB
    const int tid = threadIdx.x;
    const int nN = N >> 7;
    // bijective XCD-chunk swizzle (m204)
    int nwg = gridDim.x;
    int xcd = blockIdx.x & 7, lin = blockIdx.x >> 3;
    int q = nwg >> 3, r8 = nwg & 7;
    int swz = (xcd < r8 ? xcd * (q + 1) : r8 * (q + 1) + (xcd - r8) * q) + lin;
    const long m0 = (long)(swz / nN) * 128;
    const int n0 = (swz % nN) * 128;
    const int l = tid & 63, wv = tid >> 6;
    const int wm = (wv >> 1) * 64, wn = (wv & 1) * 64;
    const int rr = l & 15, lg = l >> 4;
    const int trow = tid >> 2;                    // row within 64-row chunk
    const int tg = (tid & 3) ^ ((tid >> 3) & 3);  // pre-swizzled source granule

    f32x4 acc[4][4];
#pragma unroll
    for (int a = 0; a < 4; ++a)
#pragma unroll
        for (int b = 0; b < 4; ++b) acc[a][b] = (f32x4){0.f, 0.f, 0.f, 0.f};

    auto stage = [&](int buf, int k0) {
#pragma unroll
        for (int c = 0; c < 2; ++c) {
            int row = c * 64 + trow;
            long arow = m0 + row;
            if (PERMA) {
                int qq = (int)arow / 49;
                int ss = (int)arow - qq * 49;
                arow = (long)ss * 1024 + qq;
            }
            gl2lds16(A + arow * lda + k0 + tg * 8, &sh[buf][0][c * 2048 + wv * 512]);
        }
#pragma unroll
        for (int c = 0; c < 2; ++c) {
            int row = c * 64 + trow;
            gl2lds16(Bt + (long)(n0 + row) * K + k0 + tg * 8, &sh[buf][1][c * 2048 + wv * 512]);
        }
    };

    const int nT = K >> 5;
    stage(0, 0);
    stage(1, 32);
    int cur = 0, sb = 2;

    for (int t = 0; t < nT; ++t) {
        if (t + 1 < nT)
            asm volatile("s_waitcnt vmcnt(4)" ::: "memory");  // tile t's loads (all waves pre-BAR)
        else
            asm volatile("s_waitcnt vmcnt(0)" ::: "memory");
        BAR();
        if (t + 2 < nT) stage(sb, (t + 2) * 32);  // buf((t-1)%3): consumed before BAR by all
        bf16x8 a[4], b[4];
#pragma unroll
        for (int mt = 0; mt < 4; ++mt) {
            int row = wm + mt * 16 + rr;
            int slot = lg ^ ((row >> 1) & 3);
            a[mt] = *(const bf16x8*)(&sh[cur][0][row * 32 + slot * 8]);
        }
#pragma unroll
        for (int nt = 0; nt < 4; ++nt) {
            int row = wn + nt * 16 + rr;
            int slot = lg ^ ((row >> 1) & 3);
            b[nt] = *(const bf16x8*)(&sh[cur][1][row * 32 + slot * 8]);
        }
#pragma unroll
        for (int mt = 0; mt < 4; ++mt)
#pragma unroll
            for (int nt = 0; nt < 4; ++nt)
                acc[mt][nt] =
                    __builtin_amdgcn_mfma_f32_16x16x32_bf16(a[mt], b[nt], acc[mt][nt], 0, 0, 0);
        cur = (cur == 2) ? 0 : cur + 1;
        sb = (sb == 2) ? 0 : sb + 1;
    }

    if (EPI == 6) {
        // ---- fused ap1: partial dot with w2, plain store per (row, n-half) ----
        const int nh = n0 >> 7;
        float w2v[4];
#pragma unroll
        for (int nt = 0; nt < 4; ++nt) w2v[nt] = w2g[n0 + wn + nt * 16 + rr];
#pragma unroll
        for (int mt = 0; mt < 4; ++mt) {
#pragma unroll
            for (int e = 0; e < 4; ++e) {
                float p = 0.f;
#pragma unroll
                for (int nt = 0; nt < 4; ++nt) {
                    int gc = n0 + wn + nt * 16 + rr;
                    p += tanhf(acc[mt][nt][e] + bias[gc]) * w2v[nt];
                }
#pragma unroll
                for (int msk = 1; msk < 16; msk <<= 1) p += __shfl_xor(p, msk);
                if (rr == 0) aPart[(m0 + wm + mt * 16 + lg * 4 + e) * 2 + nh] = p;
            }
        }
        return;
    }

    // ---- LDS-staged coalesced epilogue ----
    ushort* cs = &sh[0][0][0];  // 128x128 bf16 = 32KB
    __syncthreads();
#pragma unroll
    for (int mt = 0; mt < 4; ++mt) {
#pragma unroll
        for (int e = 0; e < 4; ++e) {
            int row = wm + mt * 16 + lg * 4 + e;
#pragma unroll
            for (int nt = 0; nt < 4; ++nt) {
                int col = wn + nt * 16 + rr;
                float v = acc[mt][nt][e] + bias[n0 + col];
                if (EPI == 0) v = fmaxf(v, 0.f);
                else if (EPI == 4) v = gelu_f(v);
                else if (EPI == 5) v = tanhf(v);
                cs[row * 128 + (((col >> 3) ^ (row & 7)) << 3) + (col & 7)] = f2b(v);
            }
        }
    }
    __syncthreads();
#pragma unroll
    for (int i = 0; i < 8; ++i) {
        int row = i * 16 + (tid >> 4);
        int gran = tid & 15;
        long gr = m0 + row;
        long orow = gr;
        if (PERMOUT) {
            int qq = (int)gr / 49;
            int ss = (int)gr - qq * 49;
            orow = (long)ss * 1024 + qq;
        }
        int4 d = *(const int4*)&cs[row * 128 + ((gran ^ (row & 7)) << 3)];
        ushort* po = outB + orow * N + n0 + gran * 8;
        if (EPI == 2 || EPI == 3) {
            const ushort* ph = (EPI == 2) ? (hresB + gr * N + n0 + gran * 8) : po;
            int4 hv = *(const int4*)ph;
            const ushort* dd = (const ushort*)&d;
            const ushort* hh = (const ushort*)&hv;
            int4 r;
            ushort* ro = (ushort*)&r;
#pragma unroll
            for (int j = 0; j < 8; ++j) {
                float x = b2f(hh[j]) + b2f(dd[j]);
                if (EPI == 2) x = gelu_f(x);
                ro[j] = f2b(x);
            }
            *(int4*)po = r;
        } else {
            *(int4*)po = d;
        }
    }
}

// ---------------------------------------------------------------------------
// LayerNorm over bf16 rows of 512 -> bf16. 256 thr = 4 waves, 1 row per wave.
// ---------------------------------------------------------------------------
__global__ __launch_bounds__(256) void ln_k(const ushort* __restrict__ x,
                                            const float* __restrict__ g,
                                            const float* __restrict__ b,
                                            ushort* __restrict__ outB) {
    long row = (long)blockIdx.x * 4 + (threadIdx.x >> 6);
    int l = threadIdx.x & 63;
    int4 u = *(const int4*)(x + row * 512 + l * 8);
    const ushort* us = (const ushort*)&u;
    float xv[8];
    float s = 0.f, qs = 0.f;
#pragma unroll
    for (int j = 0; j < 8; ++j) {
        xv[j] = b2f(us[j]);
        s += xv[j];
        qs += xv[j] * xv[j];
    }
#pragma unroll
    for (int m = 1; m < 64; m <<= 1) {
        s += __shfl_xor(s, m);
        qs += __shfl_xor(qs, m);
    }
    float mean = s * (1.f / 512.f);
    float var = qs * (1.f / 512.f) - mean * mean;
    float rstd = rsqrtf(var + 1e-5f);
    float4 g0 = *(const float4*)(g + l * 8);
    float4 g1 = *(const float4*)(g + l * 8 + 4);
    float4 b0 = *(const float4*)(b + l * 8);
    float4 b1 = *(const float4*)(b + l * 8 + 4);
    float gg[8] = {g0.x, g0.y, g0.z, g0.w, g1.x, g1.y, g1.z, g1.w};
    float bb[8] = {b0.x, b0.y, b0.z, b0.w, b1.x, b1.y, b1.z, b1.w};
    int4 pk;
    ushort* po = (ushort*)&pk;
#pragma unroll
    for (int j = 0; j < 8; ++j) po[j] = f2b((xv[j] - mean) * rstd * gg[j] + bb[j]);
    *(int4*)(&outB[row * 512 + l * 8]) = pk;
}

// ---------------------------------------------------------------------------
// Fused per-(window,head) attention. 1 wave/block, 49 tokens padded to 64.
// Q,K fragments direct from qkv; V transposed in-LDS (zero-padded).
// O staged back into vt after PV for coalesced int4 writeback.
// ---------------------------------------------------------------------------
template <bool BIAS>
__global__ __launch_bounds__(64) void attn_k(const ushort* __restrict__ qkv,
                                             const float* __restrict__ cdata,
                                             const int* __restrict__ pwt,
                                             const float* __restrict__ btg,
                                             ushort* __restrict__ outb) {
    __shared__ ushort vt[4096];
    __shared__ ushort ps[4096];
    __shared__ float cx[64], cy[64], bt[16];
    __shared__ unsigned char pwu[512];

    const int l = threadIdx.x;
    const int w = blockIdx.x >> 3, hh = blockIdx.x & 7;
    const long rowbase = (long)w * 49;
    const int rr = l & 15, lg = l >> 4;

    // V stage + transpose into vt (zero-padded tokens >= 49)
    for (int idx = l; idx < 512; idx += 64) {
        int t = idx >> 3, g = idx & 7;
        int4 zv = make_int4(0, 0, 0, 0);
        if (t < 49) zv = *(const int4*)(qkv + (rowbase + t) * 1536 + 1024 + hh * 64 + g * 8);
        ushort* pv = (ushort*)&zv;
#pragma unroll
        for (int ii = 0; ii < 8; ++ii) {
            int d = g * 8 + ii;
            vt[d * 64 + (((t >> 3) ^ ii) * 8) + (t & 7)] = pv[ii];
        }
    }
    if (BIAS) {
        if (l < 49) {
            cx[l] = cdata[(rowbase + l) * 1026];
            cy[l] = cdata[(rowbase + l) * 1026 + 1];
        }
        if (l < 15) bt[l] = btg[l * 8 + hh];
        for (int i = l; i < 512; i += 64) pwu[i] = (unsigned char)pwt[i];
    }

    // QK^T: direct global fragment loads
    f32x4 s[4][4];
#pragma unroll
    for (int a = 0; a < 4; ++a)
#pragma unroll
        for (int b = 0; b < 4; ++b) s[a][b] = (f32x4){0.f, 0.f, 0.f, 0.f};

    const bf16x8 zfrag = {0, 0, 0, 0, 0, 0, 0, 0};
#pragma unroll
    for (int kk = 0; kk < 2; ++kk) {
        bf16x8 a[4], b[4];
#pragma unroll
        for (int mt = 0; mt < 4; ++mt) {
            int i = mt * 16 + rr;
            a[mt] = (i < 49) ? *(const bf16x8*)(qkv + (rowbase + i) * 1536 + hh * 64 +
                                                (kk * 4 + lg) * 8)
                             : zfrag;
        }
#pragma unroll
        for (int nt = 0; nt < 4; ++nt) {
            int j = nt * 16 + rr;
            b[nt] = (j < 49) ? *(const bf16x8*)(qkv + (rowbase + j) * 1536 + 512 + hh * 64 +
                                                (kk * 4 + lg) * 8)
                             : zfrag;
        }
        __builtin_amdgcn_s_setprio(1);
#pragma unroll
        for (int mt = 0; mt < 4; ++mt)
#pragma unroll
            for (int nt = 0; nt < 4; ++nt)
                s[mt][nt] = __builtin_amdgcn_mfma_f32_16x16x32_bf16(a[mt], b[nt], s[mt][nt], 0, 0, 0);
        __builtin_amdgcn_s_setprio(0);
    }
    __syncthreads();

    // scale + bias + padding mask; batched softmax reductions (ILP)
    float mrow[16], srow[16];
#pragma unroll
    for (int mt = 0; mt < 4; ++mt) {
#pragma unroll
        for (int e = 0; e < 4; ++e) {
            int i = mt * 16 + lg * 4 + e;
            float mloc = -1e30f;
#pragma unroll
            for (int nt = 0; nt < 4; ++nt) {
                int j = nt * 16 + rr;
                float v = s[mt][nt][e] * 0.125f;
                if (j >= 49) {
                    v = -1e30f;
                } else if (BIAS) {
                    if (i < 49) {
                        int dx = (int)fabsf(cx[i] - cx[j]);
                        int dy = (int)fabsf(cy[i] - cy[j]);
                        v += bt[pwu[dx] + pwu[dy]];
                    }
                }
                s[mt][nt][e] = v;
                mloc = fmaxf(mloc, v);
            }
            mrow[mt * 4 + e] = mloc;
        }
    }
#pragma unroll
    for (int msk = 1; msk < 16; msk <<= 1)
#pragma unroll
        for (int r = 0; r < 16; ++r) mrow[r] = fmaxf(mrow[r], __shfl_xor(mrow[r], msk));
#pragma unroll
    for (int mt = 0; mt < 4; ++mt) {
#pragma unroll
        for (int e = 0; e < 4; ++e) {
            int r = mt * 4 + e;
            int i = mt * 16 + lg * 4 + e;
            float sm = 0.f;
#pragma unroll
            for (int nt = 0; nt < 4; ++nt) {
                int j = nt * 16 + rr;
                float p = __expf(s[mt][nt][e] - mrow[r]);
                sm += p;
                ps[i * 64 + (((j >> 3) ^ (i & 7)) * 8) + (j & 7)] = f2b(p);
            }
            srow[r] = sm;
        }
    }
#pragma unroll
    for (int msk = 1; msk < 16; msk <<= 1)
#pragma unroll
        for (int r = 0; r < 16; ++r) srow[r] += __shfl_xor(srow[r], msk);
#pragma unroll
    for (int r = 0; r < 16; ++r) srow[r] = 1.f / srow[r];
    __syncthreads();

    f32x4 o[4][4];
#pragma unroll
    for (int a = 0; a < 4; ++a)
#pragma unroll
        for (int b = 0; b < 4; ++b) o[a][b] = (f32x4){0.f, 0.f, 0.f, 0.f};

#pragma unroll
    for (int kk = 0; kk < 2; ++kk) {
        bf16x8 a[4], b[4];
#pragma unroll
        for (int mt = 0; mt < 4; ++mt) {
            int i = mt * 16 + rr;
            int slot = (kk * 4 + lg) ^ (i & 7);
            a[mt] = *(const bf16x8*)(&ps[i * 64 + slot * 8]);
        }
#pragma unroll
        for (int nt = 0; nt < 4; ++nt) {
            int d = nt * 16 + rr;
            int slot = (kk * 4 + lg) ^ (d & 7);
            b[nt] = *(const bf16x8*)(&vt[d * 64 + slot * 8]);
        }
        __builtin_amdgcn_s_setprio(1);
#pragma unroll
        for (int mt = 0; mt < 4; ++mt)
#pragma unroll
            for (int nt = 0; nt < 4; ++nt)
                o[mt][nt] = __builtin_amdgcn_mfma_f32_16x16x32_bf16(a[mt], b[nt], o[mt][nt], 0, 0, 0);
        __builtin_amdgcn_s_setprio(0);
    }

    // ---- O restage into vt (dead after PV) + coalesced int4 writeback ----
    __syncthreads();
#pragma unroll
    for (int mt = 0; mt < 4; ++mt) {
#pragma unroll
        for (int e = 0; e < 4; ++e) {
            int i = mt * 16 + lg * 4 + e;
#pragma unroll
            for (int nt = 0; nt < 4; ++nt) {
                int col = nt * 16 + rr;
                vt[i * 64 + (((col >> 3) ^ (i & 7)) << 3) + (col & 7)] =
                    f2b(o[mt][nt][e] * srow[mt * 4 + e]);
            }
        }
    }
    __syncthreads();
    for (int idx = l; idx < 392; idx += 64) {
        int row = idx >> 3, g = idx & 7;
        int4 v = *(const int4*)&vt[row * 64 + ((g ^ (row & 7)) << 3)];
        *(int4*)(outb + (rowbase + row) * 512 + hh * 64 + g * 8) = v;
    }
}

// smprep over pair-partials: A[i] = aPart[2i] + aPart[2i+1]
__global__ __launch_bounds__(1024) void smprep_k(const float* __restrict__ aPart, int M,
                                                 float* __restrict__ sc) {
    __shared__ float red[1024];
    int t = threadIdx.x;
    float m = -3.4e38f;
    for (int i = t; i < M; i += 1024) m = fmaxf(m, aPart[2 * i] + aPart[2 * i + 1]);
    red[t] = m;
    __syncthreads();
    for (int o = 512; o > 0; o >>= 1) {
        if (t < o) red[t] = fmaxf(red[t], red[t + o]);
        __syncthreads();
    }
    float mx = red[0];
    __syncthreads();
    float s = 0.f;
    for (int i = t; i < M; i += 1024) s += __expf(aPart[2 * i] + aPart[2 * i + 1] - mx);
    red[t] = s;
    __syncthreads();
    for (int o = 512; o > 0; o >>= 1) {
        if (t < o) red[t] += red[t + o];
        __syncthreads();
    }
    if (t == 0) {
        sc[0] = mx;
        sc[1] = red[0];
    }
}

__global__ __launch_bounds__(256) void pool1_k(const float* __restrict__ aPart,
                                               const float* __restrict__ sc,
                                               const ushort* __restrict__ feat,
                                               float* __restrict__ partial) {
    int t = threadIdx.x;
    long base = (long)blockIdx.x * 256;
    float mx = sc[0], rd = 1.f / sc[1];
    float a0 = 0.f, a1 = 0.f;
    for (int i = 0; i < 256; ++i) {
        long tok = base + i;
        float wt = __expf(aPart[2 * tok] + aPart[2 * tok + 1] - mx) * rd;
        a0 += wt * b2f(feat[tok * 512 + t]);
        a1 += wt * b2f(feat[tok * 512 + t + 256]);
    }
    partial[(long)blockIdx.x * 512 + t] = a0;
    partial[(long)blockIdx.x * 512 + t + 256] = a1;
}

__global__ __launch_bounds__(512) void final_k(const float* __restrict__ partial, int NP,
                                               const float* __restrict__ fc2w,
                                               const float* __restrict__ fc2b,
                                               float* __restrict__ out) {
    __shared__ float pooled[512];
    __shared__ float lgs[4];
    int t = threadIdx.x;
    float s = 0.f;
    for (int b = 0; b < NP; ++b) s += partial[(long)b * 512 + t];
    pooled[t] = s;
    __syncthreads();
    if (t < 4) {
        float x = fc2b[t];
        for (int c = 0; c < 512; ++c) x += pooled[c] * fc2w[c * 4 + t];
        lgs[t] = x;
    }
    __syncthreads();
    if (t == 0) {
        float hz[4];
        for (int i = 0; i < 4; ++i) hz[i] = 1.f / (1.f + __expf(-lgs[i]));
        for (int i = 0; i < 4; ++i) out[i] = hz[i];
        float cp = 1.f;
        for (int i = 0; i < 4; ++i) {
            cp *= (1.f - hz[i]);
            out[4 + i] = cp;
        }
        int best = 0;
        for (int i = 1; i < 4; ++i)
            if (lgs[i] > lgs[best]) best = i;
        out[8] = (float)best;
    }
}

// ---------------------------------------------------------------------------
extern "C" void kernel_launch(void* const* d_in, const int* in_sizes, int n_in, void* d_out,
                              int out_size, void* d_ws, size_t ws_size, hipStream_t stream) {
    const float* data = (const float*)d_in[0];
    const float* fc1_w = (const float*)d_in[1];
    const float* fc1_b = (const float*)d_in[2];
    const float* ln1_g = (const float*)d_in[3];
    const float* ln1_b = (const float*)d_in[4];
    const float* wa_qkv_w = (const float*)d_in[5];
    const float* wa_qkv_b = (const float*)d_in[6];
    const float* wa_bt = (const float*)d_in[7];
    const float* wa_proj_w = (const float*)d_in[8];
    const float* wa_proj_b = (const float*)d_in[9];
    const float* n1_g = (const float*)d_in[10];
    const float* n1_b = (const float*)d_in[11];
    const float* sa_qkv_w = (const float*)d_in[12];
    const float* sa_qkv_b = (const float*)d_in[13];
    const float* sa_proj_w = (const float*)d_in[14];
    const float* sa_proj_b = (const float*)d_in[15];
    const float* n2_g = (const float*)d_in[16];
    const float* n2_b = (const float*)d_in[17];
    const float* mlp_w1 = (const float*)d_in[18];
    const float* mlp_b1 = (const float*)d_in[19];
    const float* mlp_w2 = (const float*)d_in[20];
    const float* mlp_b2 = (const float*)d_in[21];
    const float* n3_g = (const float*)d_in[22];
    const float* n3_b = (const float*)d_in[23];
    const float* ap_w1 = (const float*)d_in[24];
    const float* ap_b1 = (const float*)d_in[25];
    const float* ap_w2 = (const float*)d_in[26];
    const float* ap_b2 = (const float*)d_in[27];  // unused: softmax shift-invariant
    const float* fc2_w = (const float*)d_in[28];
    const float* fc2_b = (const float*)d_in[29];
    (void)ap_b2;

    const int M = 50176;  // tokens
    const int nM = M / 128;

    char* ws = (char*)d_ws;
    size_t off = 0;
    auto alloc = [&](size_t bytes) {
        size_t p = off;
        off = (off + bytes + 255) & ~(size_t)255;
        return (void*)(ws + p);
    };

    ushort* fc1T = (ushort*)alloc((size_t)512 * 1024 * 2);
    ushort* waqkvT = (ushort*)alloc((size_t)1536 * 512 * 2);
    ushort* waprojT = (ushort*)alloc((size_t)512 * 512 * 2);
    ushort* saqkvT = (ushort*)alloc((size_t)1536 * 512 * 2);
    ushort* saprojT = (ushort*)alloc((size_t)512 * 512 * 2);
    ushort* mlp1T = (ushort*)alloc((size_t)512 * 512 * 2);
    ushort* mlp2T = (ushort*)alloc((size_t)512 * 512 * 2);
    ushort* ap1T = (ushort*)alloc((size_t)256 * 512 * 2);
    int* pwtab = (int*)alloc(512 * 4);
    float* sc = (float*)alloc(64);
    float* aPart = (float*)alloc((size_t)M * 2 * 4);  // [M][2] n-half partials
    float* partial = (float*)alloc((size_t)196 * 512 * 4);
    ushort* hbB = (ushort*)alloc((size_t)M * 512 * 2);  // h (bf16)
    ushort* fbB = (ushort*)alloc((size_t)M * 512 * 2);  // f (bf16)
    ushort* lnb = (ushort*)alloc((size_t)M * 512 * 2);  // LN output (bf16)
    ushort* attnout = (ushort*)alloc((size_t)M * 512 * 2);
    ushort* qkvb = (ushort*)alloc((size_t)M * 1536 * 2);
    ushort* dataB = qkvb;  // [M][1024] bf16, dead once WA qkv runs

    // data cast + all weight transposes + pw table in ONE launch
    prep_k<<<37890, 256, 0, stream>>>(data, dataB, pwtab, fc1_w, fc1T, wa_qkv_w, waqkvT,
                                      wa_proj_w, waprojT, sa_qkv_w, saqkvT, sa_proj_w, saprojT,
                                      mlp_w1, mlp1T, mlp_w2, mlp2T, ap_w1, ap1T);

    // fc1 + relu -> h (bf16)
    gemm_k<0, false, false><<<nM * 4, 256, 0, stream>>>(dataB, 1024, fc1T, fc1_b, nullptr, hbB,
                                                        nullptr, nullptr, 512, 1024);
    // ln1(h) -> lnb
    ln_k<<<M / 4, 256, 0, stream>>>(hbB, ln1_g, ln1_b, lnb);
    // WA qkv
    gemm_k<1, false, false><<<nM * 12, 256, 0, stream>>>(lnb, 512, waqkvT, wa_qkv_b, nullptr,
                                                         qkvb, nullptr, nullptr, 1536, 512);
    // WA attention (with bias)
    attn_k<true><<<8192, 64, 0, stream>>>(qkvb, data, pwtab, wa_bt, attnout);
    // WA proj: f = gelu(h + out)  (bf16)
    gemm_k<2, false, false><<<nM * 4, 256, 0, stream>>>(attnout, 512, waprojT, wa_proj_b, hbB,
                                                        fbB, nullptr, nullptr, 512, 512);
    // norm1(f) -> lnb
    ln_k<<<M / 4, 256, 0, stream>>>(fbB, n1_g, n1_b, lnb);
    // SA qkv (permuted gather of A rows)
    gemm_k<1, true, false><<<nM * 12, 256, 0, stream>>>(lnb, 512, saqkvT, sa_qkv_b, nullptr,
                                                        qkvb, nullptr, nullptr, 1536, 512);
    // SA attention (no bias)
    attn_k<false><<<8192, 64, 0, stream>>>(qkvb, nullptr, nullptr, nullptr, attnout);
    // SA proj: f[perm] += out
    gemm_k<3, false, true><<<nM * 4, 256, 0, stream>>>(attnout, 512, saprojT, sa_proj_b, nullptr,
                                                       fbB, nullptr, nullptr, 512, 512);
    // norm2(f) -> lnb
    ln_k<<<M / 4, 256, 0, stream>>>(fbB, n2_g, n2_b, lnb);
    // mlp1: hidden = gelu(lnb @ w1 + b1) -> attnout
    gemm_k<4, false, false><<<nM * 4, 256, 0, stream>>>(lnb, 512, mlp1T, mlp_b1, nullptr, attnout,
                                                        nullptr, nullptr, 512, 512);
    // mlp2: f += hidden @ w2 + b2
    gemm_k<3, false, false><<<nM * 4, 256, 0, stream>>>(attnout, 512, mlp2T, mlp_b2, nullptr, fbB,
                                                        nullptr, nullptr, 512, 512);
    // norm3(f) -> lnb (feat for ap1 AND pooling)
    ln_k<<<M / 4, 256, 0, stream>>>(fbB, n3_g, n3_b, lnb);
    // ap1+ap2 fused: aPart[row][nh] = tanh(lnb @ ap_w1 + b1) . ap_w2[half]
    gemm_k<6, false, false><<<nM * 2, 256, 0, stream>>>(lnb, 512, ap1T, ap_b1, nullptr, nullptr,
                                                        ap_w2, aPart, 256, 512);
    // softmax prep
    smprep_k<<<1, 1024, 0, stream>>>(aPart, M, sc);
    // pooled partials (feat = lnb, bf16)
    pool1_k<<<196, 256, 0, stream>>>(aPart, sc, lnb, partial);
    // final head
    final_k<<<1, 512, 0, stream>>>(partial, 196, fc2_w, fc2_b, (float*)d_out);
}

// Round 17
// 942.242 us; speedup vs baseline: 1.0405x; 1.0405x over previous
//
#include <hip/hip_runtime.h>
#include <hip/hip_bf16.h>
#include <math.h>

typedef short bf16x8 __attribute__((ext_vector_type(8)));
typedef float f32x4 __attribute__((ext_vector_type(4)));

#define DEV __device__ __forceinline__

DEV ushort f2b(float x) {
    unsigned u = __float_as_uint(x);
    u += 0x7fffu + ((u >> 16) & 1u);
    return (ushort)(u >> 16);
}
DEV float b2f(ushort h) { return __uint_as_float(((unsigned)h) << 16); }
// fast tanh: 1 - 2/(e^{2x}+1); e->inf => 1, e->0 => -1 (overflow-safe, no NaN)
DEV float ftanh(float x) {
    float e = __expf(2.f * x);
    return 1.f - 2.f / (e + 1.f);
}
// tanh-form gelu (max abs err vs erf-gelu ~3e-4, << bf16 rounding)
DEV float gelu_f(float x) {
    return 0.5f * x * (1.f + ftanh(0.7978845608028654f * (x + 0.044715f * x * x * x)));
}

// async global->LDS, 16B per lane; LDS dest wave-uniform base (lane*16 added by HW)
DEV void gl2lds16(const void* g, void* l) {
    __builtin_amdgcn_global_load_lds(
        (const __attribute__((address_space(1))) void*)(uintptr_t)g,
        (__attribute__((address_space(3))) void*)(uintptr_t)l, 16, 0, 0);
}

#define BAR() __builtin_amdgcn_s_barrier()

// ---------------------------------------------------------------------------
// prep_k: data cast + ALL weight transposes + pw table in ONE launch.
// Blocks [0,25088): dcast; [25088,37888): weight casts; [37888,37890): pw.
// ---------------------------------------------------------------------------
DEV void cast1(const float* __restrict__ W, ushort* __restrict__ Wt, int K, int N, long i) {
    int k = (int)(i / N), n = (int)(i % N);
    Wt[(long)n * K + k] = f2b(W[i]);
}
__global__ __launch_bounds__(256) void prep_k(
    const float* __restrict__ data, ushort* __restrict__ dataB, int* __restrict__ pw,
    const float* s0, ushort* d0, const float* s1, ushort* d1, const float* s2, ushort* d2,
    const float* s3, ushort* d3, const float* s4, ushort* d4, const float* s5, ushort* d5,
    const float* s6, ushort* d6, const float* s7, ushort* d7) {
    int blk = blockIdx.x;
    if (blk < 25088) {
        long i = ((long)blk * 256 + threadIdx.x) * 8;
        int r = (int)(i >> 10);
        int c = (int)(i & 1023);
        const float* p = data + (long)r * 1026 + 2 + c;
        float2 f0 = *(const float2*)p;
        float2 f1 = *(const float2*)(p + 2);
        float2 f2 = *(const float2*)(p + 4);
        float2 f3 = *(const float2*)(p + 6);
        int4 pk;
        pk.x = (int)f2b(f0.x) | ((int)f2b(f0.y) << 16);
        pk.y = (int)f2b(f1.x) | ((int)f2b(f1.y) << 16);
        pk.z = (int)f2b(f2.x) | ((int)f2b(f2.y) << 16);
        pk.w = (int)f2b(f3.x) | ((int)f2b(f3.y) << 16);
        *(int4*)(&dataB[i]) = pk;
    } else if (blk < 37888) {
        long i = (long)(blk - 25088) * 256 + threadIdx.x;
        if (i < 524288) cast1(s0, d0, 1024, 512, i);                  // fc1
        else if (i < 1310720) cast1(s1, d1, 512, 1536, i - 524288);   // wa qkv
        else if (i < 1572864) cast1(s2, d2, 512, 512, i - 1310720);   // wa proj
        else if (i < 2359296) cast1(s3, d3, 512, 1536, i - 1572864);  // sa qkv
        else if (i < 2621440) cast1(s4, d4, 512, 512, i - 2359296);   // sa proj
        else if (i < 2883584) cast1(s5, d5, 512, 512, i - 2621440);   // mlp1
        else if (i < 3145728) cast1(s6, d6, 512, 512, i - 2883584);   // mlp2
        else cast1(s7, d7, 512, 256, i - 3145728);                    // ap1
    } else {
        int d = (blk - 37888) * 256 + threadIdx.x;
        if (d < 512) {
            int v;
            if (d == 0) v = 0;
            else if (d <= 3) v = 1;
            else {
                float t = logf((float)d / 1.9f) / 1.7917594692280552f * 3.8f;
                int r = (int)rintf(t);
                v = r < 7 ? r : 7;
            }
            pw[d] = v;
        }
    }
}

// ---------------------------------------------------------------------------
// GEMM: C[M x N] = A[M x K] @ B[K x N] (+bias, epilogues). A bf16, out bf16.
// BM=BN=128, BK=32, 4 waves, 16x16x32 MFMA.
// FROZEN round-13 K-loop: 3-buffer A+B gl2lds16, single barrier, counted
// vmcnt(4) (prefetch distance 2). Schedule experiments closed (r5/7/13/14).
// LDS-staged coalesced epilogue (C tile -> LDS -> int4 flat writeback).
// EPI: 0 relu  1 plain  2 gelu(hres+x)  3 out[perm?] += x  4 gelu  5 tanh
//      6 ap1-fused: aPart[row*2 + (n0>>7)] = sum_col tanh(acc+bias)*w2[col]
// ---------------------------------------------------------------------------
template <int EPI, bool PERMA, bool PERMOUT>
__global__ __launch_bounds__(256, 3) void gemm_k(const ushort* __restrict__ A, long lda,
                                                 const ushort* __restrict__ Bt,
                                                 const float* __restrict__ bias,
                                                 const ushort* __restrict__ hresB,
                                                 ushort* __restrict__ outB,
                                                 const float* __restrict__ w2g,
                                                 float* __restrict__ aPart, int N, int K) {
    __shared__ ushort sh[3][2][128 * 32];  // 48 KB
    const int tid = threadIdx.x;
    const int nN = N >> 7;
    // bijective XCD-chunk swizzle (m204)
    int nwg = gridDim.x;
    int xcd = blockIdx.x & 7, lin = blockIdx.x >> 3;
    int q = nwg >> 3, r8 = nwg & 7;
    int swz = (xcd < r8 ? xcd * (q + 1) : r8 * (q + 1) + (xcd - r8) * q) + lin;
    const long m0 = (long)(swz / nN) * 128;
    const int n0 = (swz % nN) * 128;
    const int l = tid & 63, wv = tid >> 6;
    const int wm = (wv >> 1) * 64, wn = (wv & 1) * 64;
    const int rr = l & 15, lg = l >> 4;
    const int trow = tid >> 2;                    // row within 64-row chunk
    const int tg = (tid & 3) ^ ((tid >> 3) & 3);  // pre-swizzled source granule

    f32x4 acc[4][4];
#pragma unroll
    for (int a = 0; a < 4; ++a)
#pragma unroll
        for (int b = 0; b < 4; ++b) acc[a][b] = (f32x4){0.f, 0.f, 0.f, 0.f};

    auto stage = [&](int buf, int k0) {
#pragma unroll
        for (int c = 0; c < 2; ++c) {
            int row = c * 64 + trow;
            long arow = m0 + row;
            if (PERMA) {
                int qq = (int)arow / 49;
                int ss = (int)arow - qq * 49;
                arow = (long)ss * 1024 + qq;
            }
            gl2lds16(A + arow * lda + k0 + tg * 8, &sh[buf][0][c * 2048 + wv * 512]);
        }
#pragma unroll
        for (int c = 0; c < 2; ++c) {
            int row = c * 64 + trow;
            gl2lds16(Bt + (long)(n0 + row) * K + k0 + tg * 8, &sh[buf][1][c * 2048 + wv * 512]);
        }
    };

    const int nT = K >> 5;
    stage(0, 0);
    stage(1, 32);
    int cur = 0, sb = 2;

    for (int t = 0; t < nT; ++t) {
        if (t + 1 < nT)
            asm volatile("s_waitcnt vmcnt(4)" ::: "memory");
        else
            asm volatile("s_waitcnt vmcnt(0)" ::: "memory");
        BAR();
        if (t + 2 < nT) stage(sb, (t + 2) * 32);
        bf16x8 a[4], b[4];
#pragma unroll
        for (int mt = 0; mt < 4; ++mt) {
            int row = wm + mt * 16 + rr;
            int slot = lg ^ ((row >> 1) & 3);
            a[mt] = *(const bf16x8*)(&sh[cur][0][row * 32 + slot * 8]);
        }
#pragma unroll
        for (int nt = 0; nt < 4; ++nt) {
            int row = wn + nt * 16 + rr;
            int slot = lg ^ ((row >> 1) & 3);
            b[nt] = *(const bf16x8*)(&sh[cur][1][row * 32 + slot * 8]);
        }
#pragma unroll
        for (int mt = 0; mt < 4; ++mt)
#pragma unroll
            for (int nt = 0; nt < 4; ++nt)
                acc[mt][nt] =
                    __builtin_amdgcn_mfma_f32_16x16x32_bf16(a[mt], b[nt], acc[mt][nt], 0, 0, 0);
        cur = (cur == 2) ? 0 : cur + 1;
        sb = (sb == 2) ? 0 : sb + 1;
    }

    if (EPI == 6) {
        // ---- fused ap1: partial dot with w2, plain store per (row, n-half) ----
        const int nh = n0 >> 7;
        float w2v[4];
#pragma unroll
        for (int nt = 0; nt < 4; ++nt) w2v[nt] = w2g[n0 + wn + nt * 16 + rr];
#pragma unroll
        for (int mt = 0; mt < 4; ++mt) {
#pragma unroll
            for (int e = 0; e < 4; ++e) {
                float p = 0.f;
#pragma unroll
                for (int nt = 0; nt < 4; ++nt) {
                    int gc = n0 + wn + nt * 16 + rr;
                    p += ftanh(acc[mt][nt][e] + bias[gc]) * w2v[nt];
                }
#pragma unroll
                for (int msk = 1; msk < 16; msk <<= 1) p += __shfl_xor(p, msk);
                if (rr == 0) aPart[(m0 + wm + mt * 16 + lg * 4 + e) * 2 + nh] = p;
            }
        }
        return;
    }

    // ---- LDS-staged coalesced epilogue ----
    ushort* cs = &sh[0][0][0];  // 128x128 bf16 = 32KB
    __syncthreads();
#pragma unroll
    for (int mt = 0; mt < 4; ++mt) {
#pragma unroll
        for (int e = 0; e < 4; ++e) {
            int row = wm + mt * 16 + lg * 4 + e;
#pragma unroll
            for (int nt = 0; nt < 4; ++nt) {
                int col = wn + nt * 16 + rr;
                float v = acc[mt][nt][e] + bias[n0 + col];
                if (EPI == 0) v = fmaxf(v, 0.f);
                else if (EPI == 4) v = gelu_f(v);
                else if (EPI == 5) v = ftanh(v);
                cs[row * 128 + (((col >> 3) ^ (row & 7)) << 3) + (col & 7)] = f2b(v);
            }
        }
    }
    __syncthreads();
#pragma unroll
    for (int i = 0; i < 8; ++i) {
        int row = i * 16 + (tid >> 4);
        int gran = tid & 15;
        long gr = m0 + row;
        long orow = gr;
        if (PERMOUT) {
            int qq = (int)gr / 49;
            int ss = (int)gr - qq * 49;
            orow = (long)ss * 1024 + qq;
        }
        int4 d = *(const int4*)&cs[row * 128 + ((gran ^ (row & 7)) << 3)];
        ushort* po = outB + orow * N + n0 + gran * 8;
        if (EPI == 2 || EPI == 3) {
            const ushort* ph = (EPI == 2) ? (hresB + gr * N + n0 + gran * 8) : po;
            int4 hv = *(const int4*)ph;
            const ushort* dd = (const ushort*)&d;
            const ushort* hh = (const ushort*)&hv;
            int4 r;
            ushort* ro = (ushort*)&r;
#pragma unroll
            for (int j = 0; j < 8; ++j) {
                float x = b2f(hh[j]) + b2f(dd[j]);
                if (EPI == 2) x = gelu_f(x);
                ro[j] = f2b(x);
            }
            *(int4*)po = r;
        } else {
            *(int4*)po = d;
        }
    }
}

// ---------------------------------------------------------------------------
// LayerNorm over bf16 rows of 512 -> bf16. 256 thr = 4 waves, 1 row per wave.
// ---------------------------------------------------------------------------
__global__ __launch_bounds__(256) void ln_k(const ushort* __restrict__ x,
                                            const float* __restrict__ g,
                                            const float* __restrict__ b,
                                            ushort* __restrict__ outB) {
    long row = (long)blockIdx.x * 4 + (threadIdx.x >> 6);
    int l = threadIdx.x & 63;
    int4 u = *(const int4*)(x + row * 512 + l * 8);
    const ushort* us = (const ushort*)&u;
    float xv[8];
    float s = 0.f, qs = 0.f;
#pragma unroll
    for (int j = 0; j < 8; ++j) {
        xv[j] = b2f(us[j]);
        s += xv[j];
        qs += xv[j] * xv[j];
    }
#pragma unroll
    for (int m = 1; m < 64; m <<= 1) {
        s += __shfl_xor(s, m);
        qs += __shfl_xor(qs, m);
    }
    float mean = s * (1.f / 512.f);
    float var = qs * (1.f / 512.f) - mean * mean;
    float rstd = rsqrtf(var + 1e-5f);
    float4 g0 = *(const float4*)(g + l * 8);
    float4 g1 = *(const float4*)(g + l * 8 + 4);
    float4 b0 = *(const float4*)(b + l * 8);
    float4 b1 = *(const float4*)(b + l * 8 + 4);
    float gg[8] = {g0.x, g0.y, g0.z, g0.w, g1.x, g1.y, g1.z, g1.w};
    float bb[8] = {b0.x, b0.y, b0.z, b0.w, b1.x, b1.y, b1.z, b1.w};
    int4 pk;
    ushort* po = (ushort*)&pk;
#pragma unroll
    for (int j = 0; j < 8; ++j) po[j] = f2b((xv[j] - mean) * rstd * gg[j] + bb[j]);
    *(int4*)(&outB[row * 512 + l * 8]) = pk;
}

// ---------------------------------------------------------------------------
// Fused per-(window,head) attention. 1 wave/block, 49 tokens padded to 64.
// Q,K fragments direct from qkv; V transposed in-LDS (zero-padded).
// O staged back into vt after PV for coalesced int4 writeback.
// ---------------------------------------------------------------------------
template <bool BIAS>
__global__ __launch_bounds__(64) void attn_k(const ushort* __restrict__ qkv,
                                             const float* __restrict__ cdata,
                                             const int* __restrict__ pwt,
                                             const float* __restrict__ btg,
                                             ushort* __restrict__ outb) {
    __shared__ ushort vt[4096];
    __shared__ ushort ps[4096];
    __shared__ float cx[64], cy[64], bt[16];
    __shared__ unsigned char pwu[512];

    const int l = threadIdx.x;
    const int w = blockIdx.x >> 3, hh = blockIdx.x & 7;
    const long rowbase = (long)w * 49;
    const int rr = l & 15, lg = l >> 4;

    // V stage + transpose into vt (zero-padded tokens >= 49)
    for (int idx = l; idx < 512; idx += 64) {
        int t = idx >> 3, g = idx & 7;
        int4 zv = make_int4(0, 0, 0, 0);
        if (t < 49) zv = *(const int4*)(qkv + (rowbase + t) * 1536 + 1024 + hh * 64 + g * 8);
        ushort* pv = (ushort*)&zv;
#pragma unroll
        for (int ii = 0; ii < 8; ++ii) {
            int d = g * 8 + ii;
            vt[d * 64 + (((t >> 3) ^ ii) * 8) + (t & 7)] = pv[ii];
        }
    }
    if (BIAS) {
        if (l < 49) {
            cx[l] = cdata[(rowbase + l) * 1026];
            cy[l] = cdata[(rowbase + l) * 1026 + 1];
        }
        if (l < 15) bt[l] = btg[l * 8 + hh];
        for (int i = l; i < 512; i += 64) pwu[i] = (unsigned char)pwt[i];
    }

    // QK^T: direct global fragment loads
    f32x4 s[4][4];
#pragma unroll
    for (int a = 0; a < 4; ++a)
#pragma unroll
        for (int b = 0; b < 4; ++b) s[a][b] = (f32x4){0.f, 0.f, 0.f, 0.f};

    const bf16x8 zfrag = {0, 0, 0, 0, 0, 0, 0, 0};
#pragma unroll
    for (int kk = 0; kk < 2; ++kk) {
        bf16x8 a[4], b[4];
#pragma unroll
        for (int mt = 0; mt < 4; ++mt) {
            int i = mt * 16 + rr;
            a[mt] = (i < 49) ? *(const bf16x8*)(qkv + (rowbase + i) * 1536 + hh * 64 +
                                                (kk * 4 + lg) * 8)
                             : zfrag;
        }
#pragma unroll
        for (int nt = 0; nt < 4; ++nt) {
            int j = nt * 16 + rr;
            b[nt] = (j < 49) ? *(const bf16x8*)(qkv + (rowbase + j) * 1536 + 512 + hh * 64 +
                                                (kk * 4 + lg) * 8)
                             : zfrag;
        }
        __builtin_amdgcn_s_setprio(1);
#pragma unroll
        for (int mt = 0; mt < 4; ++mt)
#pragma unroll
            for (int nt = 0; nt < 4; ++nt)
                s[mt][nt] = __builtin_amdgcn_mfma_f32_16x16x32_bf16(a[mt], b[nt], s[mt][nt], 0, 0, 0);
        __builtin_amdgcn_s_setprio(0);
    }
    __syncthreads();

    // scale + bias + padding mask; batched softmax reductions (ILP)
    float mrow[16], srow[16];
#pragma unroll
    for (int mt = 0; mt < 4; ++mt) {
#pragma unroll
        for (int e = 0; e < 4; ++e) {
            int i = mt * 16 + lg * 4 + e;
            float mloc = -1e30f;
#pragma unroll
            for (int nt = 0; nt < 4; ++nt) {
                int j = nt * 16 + rr;
                float v = s[mt][nt][e] * 0.125f;
                if (j >= 49) {
                    v = -1e30f;
                } else if (BIAS) {
                    if (i < 49) {
                        int dx = (int)fabsf(cx[i] - cx[j]);
                        int dy = (int)fabsf(cy[i] - cy[j]);
                        v += bt[pwu[dx] + pwu[dy]];
                    }
                }
                s[mt][nt][e] = v;
                mloc = fmaxf(mloc, v);
            }
            mrow[mt * 4 + e] = mloc;
        }
    }
#pragma unroll
    for (int msk = 1; msk < 16; msk <<= 1)
#pragma unroll
        for (int r = 0; r < 16; ++r) mrow[r] = fmaxf(mrow[r], __shfl_xor(mrow[r], msk));
#pragma unroll
    for (int mt = 0; mt < 4; ++mt) {
#pragma unroll
        for (int e = 0; e < 4; ++e) {
            int r = mt * 4 + e;
            int i = mt * 16 + lg * 4 + e;
            float sm = 0.f;
#pragma unroll
            for (int nt = 0; nt < 4; ++nt) {
                int j = nt * 16 + rr;
                float p = __expf(s[mt][nt][e] - mrow[r]);
                sm += p;
                ps[i * 64 + (((j >> 3) ^ (i & 7)) * 8) + (j & 7)] = f2b(p);
            }
            srow[r] = sm;
        }
    }
#pragma unroll
    for (int msk = 1; msk < 16; msk <<= 1)
#pragma unroll
        for (int r = 0; r < 16; ++r) srow[r] += __shfl_xor(srow[r], msk);
#pragma unroll
    for (int r = 0; r < 16; ++r) srow[r] = 1.f / srow[r];
    __syncthreads();

    f32x4 o[4][4];
#pragma unroll
    for (int a = 0; a < 4; ++a)
#pragma unroll
        for (int b = 0; b < 4; ++b) o[a][b] = (f32x4){0.f, 0.f, 0.f, 0.f};

#pragma unroll
    for (int kk = 0; kk < 2; ++kk) {
        bf16x8 a[4], b[4];
#pragma unroll
        for (int mt = 0; mt < 4; ++mt) {
            int i = mt * 16 + rr;
            int slot = (kk * 4 + lg) ^ (i & 7);
            a[mt] = *(const bf16x8*)(&ps[i * 64 + slot * 8]);
        }
#pragma unroll
        for (int nt = 0; nt < 4; ++nt) {
            int d = nt * 16 + rr;
            int slot = (kk * 4 + lg) ^ (d & 7);
            b[nt] = *(const bf16x8*)(&vt[d * 64 + slot * 8]);
        }
        __builtin_amdgcn_s_setprio(1);
#pragma unroll
        for (int mt = 0; mt < 4; ++mt)
#pragma unroll
            for (int nt = 0; nt < 4; ++nt)
                o[mt][nt] = __builtin_amdgcn_mfma_f32_16x16x32_bf16(a[mt], b[nt], o[mt][nt], 0, 0, 0);
        __builtin_amdgcn_s_setprio(0);
    }

    // ---- O restage into vt (dead after PV) + coalesced int4 writeback ----
    __syncthreads();
#pragma unroll
    for (int mt = 0; mt < 4; ++mt) {
#pragma unroll
        for (int e = 0; e < 4; ++e) {
            int i = mt * 16 + lg * 4 + e;
#pragma unroll
            for (int nt = 0; nt < 4; ++nt) {
                int col = nt * 16 + rr;
                vt[i * 64 + (((col >> 3) ^ (i & 7)) << 3) + (col & 7)] =
                    f2b(o[mt][nt][e] * srow[mt * 4 + e]);
            }
        }
    }
    __syncthreads();
    for (int idx = l; idx < 392; idx += 64) {
        int row = idx >> 3, g = idx & 7;
        int4 v = *(const int4*)&vt[row * 64 + ((g ^ (row & 7)) << 3)];
        *(int4*)(outb + (rowbase + row) * 512 + hh * 64 + g * 8) = v;
    }
}

// smprep over pair-partials: A[i] = aPart[2i] + aPart[2i+1]
__global__ __launch_bounds__(1024) void smprep_k(const float* __restrict__ aPart, int M,
                                                 float* __restrict__ sc) {
    __shared__ float red[1024];
    int t = threadIdx.x;
    float m = -3.4e38f;
    for (int i = t; i < M; i += 1024) m = fmaxf(m, aPart[2 * i] + aPart[2 * i + 1]);
    red[t] = m;
    __syncthreads();
    for (int o = 512; o > 0; o >>= 1) {
        if (t < o) red[t] = fmaxf(red[t], red[t + o]);
        __syncthreads();
    }
    float mx = red[0];
    __syncthreads();
    float s = 0.f;
    for (int i = t; i < M; i += 1024) s += __expf(aPart[2 * i] + aPart[2 * i + 1] - mx);
    red[t] = s;
    __syncthreads();
    for (int o = 512; o > 0; o >>= 1) {
        if (t < o) red[t] += red[t + o];
        __syncthreads();
    }
    if (t == 0) {
        sc[0] = mx;
        sc[1] = red[0];
    }
}

// pool: stage per-token weights in LDS once per block (was 256x redundant expf)
__global__ __launch_bounds__(256) void pool1_k(const float* __restrict__ aPart,
                                               const float* __restrict__ sc,
                                               const ushort* __restrict__ feat,
                                               float* __restrict__ partial) {
    __shared__ float wt[256];
    int t = threadIdx.x;
    long base = (long)blockIdx.x * 256;
    float mx = sc[0], rd = 1.f / sc[1];
    {
        long tok = base + t;
        wt[t] = __expf(aPart[2 * tok] + aPart[2 * tok + 1] - mx) * rd;
    }
    __syncthreads();
    float a0 = 0.f, a1 = 0.f;
    for (int i = 0; i < 256; ++i) {
        long tok = base + i;
        float w = wt[i];
        a0 += w * b2f(feat[tok * 512 + t]);
        a1 += w * b2f(feat[tok * 512 + t + 256]);
    }
    partial[(long)blockIdx.x * 512 + t] = a0;
    partial[(long)blockIdx.x * 512 + t + 256] = a1;
}

__global__ __launch_bounds__(512) void final_k(const float* __restrict__ partial, int NP,
                                               const float* __restrict__ fc2w,
                                               const float* __restrict__ fc2b,
                                               float* __restrict__ out) {
    __shared__ float pooled[512];
    __shared__ float lgs[4];
    int t = threadIdx.x;
    float s = 0.f;
    for (int b = 0; b < NP; ++b) s += partial[(long)b * 512 + t];
    pooled[t] = s;
    __syncthreads();
    if (t < 4) {
        float x = fc2b[t];
        for (int c = 0; c < 512; ++c) x += pooled[c] * fc2w[c * 4 + t];
        lgs[t] = x;
    }
    __syncthreads();
    if (t == 0) {
        float hz[4];
        for (int i = 0; i < 4; ++i) hz[i] = 1.f / (1.f + __expf(-lgs[i]));
        for (int i = 0; i < 4; ++i) out[i] = hz[i];
        float cp = 1.f;
        for (int i = 0; i < 4; ++i) {
            cp *= (1.f - hz[i]);
            out[4 + i] = cp;
        }
        int best = 0;
        for (int i = 1; i < 4; ++i)
            if (lgs[i] > lgs[best]) best = i;
        out[8] = (float)best;
    }
}

// ---------------------------------------------------------------------------
extern "C" void kernel_launch(void* const* d_in, const int* in_sizes, int n_in, void* d_out,
                              int out_size, void* d_ws, size_t ws_size, hipStream_t stream) {
    const float* data = (const float*)d_in[0];
    const float* fc1_w = (const float*)d_in[1];
    const float* fc1_b = (const float*)d_in[2];
    const float* ln1_g = (const float*)d_in[3];
    const float* ln1_b = (const float*)d_in[4];
    const float* wa_qkv_w = (const float*)d_in[5];
    const float* wa_qkv_b = (const float*)d_in[6];
    const float* wa_bt = (const float*)d_in[7];
    const float* wa_proj_w = (const float*)d_in[8];
    const float* wa_proj_b = (const float*)d_in[9];
    const float* n1_g = (const float*)d_in[10];
    const float* n1_b = (const float*)d_in[11];
    const float* sa_qkv_w = (const float*)d_in[12];
    const float* sa_qkv_b = (const float*)d_in[13];
    const float* sa_proj_w = (const float*)d_in[14];
    const float* sa_proj_b = (const float*)d_in[15];
    const float* n2_g = (const float*)d_in[16];
    const float* n2_b = (const float*)d_in[17];
    const float* mlp_w1 = (const float*)d_in[18];
    const float* mlp_b1 = (const float*)d_in[19];
    const float* mlp_w2 = (const float*)d_in[20];
    const float* mlp_b2 = (const float*)d_in[21];
    const float* n3_g = (const float*)d_in[22];
    const float* n3_b = (const float*)d_in[23];
    const float* ap_w1 = (const float*)d_in[24];
    const float* ap_b1 = (const float*)d_in[25];
    const float* ap_w2 = (const float*)d_in[26];
    const float* ap_b2 = (const float*)d_in[27];  // unused: softmax shift-invariant
    const float* fc2_w = (const float*)d_in[28];
    const float* fc2_b = (const float*)d_in[29];
    (void)ap_b2;

    const int M = 50176;  // tokens
    const int nM = M / 128;

    char* ws = (char*)d_ws;
    size_t off = 0;
    auto alloc = [&](size_t bytes) {
        size_t p = off;
        off = (off + bytes + 255) & ~(size_t)255;
        return (void*)(ws + p);
    };

    ushort* fc1T = (ushort*)alloc((size_t)512 * 1024 * 2);
    ushort* waqkvT = (ushort*)alloc((size_t)1536 * 512 * 2);
    ushort* waprojT = (ushort*)alloc((size_t)512 * 512 * 2);
    ushort* saqkvT = (ushort*)alloc((size_t)1536 * 512 * 2);
    ushort* saprojT = (ushort*)alloc((size_t)512 * 512 * 2);
    ushort* mlp1T = (ushort*)alloc((size_t)512 * 512 * 2);
    ushort* mlp2T = (ushort*)alloc((size_t)512 * 512 * 2);
    ushort* ap1T = (ushort*)alloc((size_t)256 * 512 * 2);
    int* pwtab = (int*)alloc(512 * 4);
    float* sc = (float*)alloc(64);
    float* aPart = (float*)alloc((size_t)M * 2 * 4);  // [M][2] n-half partials
    float* partial = (float*)alloc((size_t)196 * 512 * 4);
    ushort* hbB = (ushort*)alloc((size_t)M * 512 * 2);  // h (bf16)
    ushort* fbB = (ushort*)alloc((size_t)M * 512 * 2);  // f (bf16)
    ushort* lnb = (ushort*)alloc((size_t)M * 512 * 2);  // LN output (bf16)
    ushort* attnout = (ushort*)alloc((size_t)M * 512 * 2);
    ushort* qkvb = (ushort*)alloc((size_t)M * 1536 * 2);
    ushort* dataB = qkvb;  // [M][1024] bf16, dead once WA qkv runs

    // data cast + all weight transposes + pw table in ONE launch
    prep_k<<<37890, 256, 0, stream>>>(data, dataB, pwtab, fc1_w, fc1T, wa_qkv_w, waqkvT,
                                      wa_proj_w, waprojT, sa_qkv_w, saqkvT, sa_proj_w, saprojT,
                                      mlp_w1, mlp1T, mlp_w2, mlp2T, ap_w1, ap1T);

    // fc1 + relu -> h (bf16)
    gemm_k<0, false, false><<<nM * 4, 256, 0, stream>>>(dataB, 1024, fc1T, fc1_b, nullptr, hbB,
                                                        nullptr, nullptr, 512, 1024);
    // ln1(h) -> lnb
    ln_k<<<M / 4, 256, 0, stream>>>(hbB, ln1_g, ln1_b, lnb);
    // WA qkv
    gemm_k<1, false, false><<<nM * 12, 256, 0, stream>>>(lnb, 512, waqkvT, wa_qkv_b, nullptr,
                                                         qkvb, nullptr, nullptr, 1536, 512);
    // WA attention (with bias)
    attn_k<true><<<8192, 64, 0, stream>>>(qkvb, data, pwtab, wa_bt, attnout);
    // WA proj: f = gelu(h + out)  (bf16)
    gemm_k<2, false, false><<<nM * 4, 256, 0, stream>>>(attnout, 512, waprojT, wa_proj_b, hbB,
                                                        fbB, nullptr, nullptr, 512, 512);
    // norm1(f) -> lnb
    ln_k<<<M / 4, 256, 0, stream>>>(fbB, n1_g, n1_b, lnb);
    // SA qkv (permuted gather of A rows)
    gemm_k<1, true, false><<<nM * 12, 256, 0, stream>>>(lnb, 512, saqkvT, sa_qkv_b, nullptr,
                                                        qkvb, nullptr, nullptr, 1536, 512);
    // SA attention (no bias)
    attn_k<false><<<8192, 64, 0, stream>>>(qkvb, nullptr, nullptr, nullptr, attnout);
    // SA proj: f[perm] += out
    gemm_k<3, false, true><<<nM * 4, 256, 0, stream>>>(attnout, 512, saprojT, sa_proj_b, nullptr,
                                                       fbB, nullptr, nullptr, 512, 512);
    // norm2(f) -> lnb
    ln_k<<<M / 4, 256, 0, stream>>>(fbB, n2_g, n2_b, lnb);
    // mlp1: hidden = gelu(lnb @ w1 + b1) -> attnout
    gemm_k<4, false, false><<<nM * 4, 256, 0, stream>>>(lnb, 512, mlp1T, mlp_b1, nullptr, attnout,
                                                        nullptr, nullptr, 512, 512);
    // mlp2: f += hidden @ w2 + b2
    gemm_k<3, false, false><<<nM * 4, 256, 0, stream>>>(attnout, 512, mlp2T, mlp_b2, nullptr, fbB,
                                                        nullptr, nullptr, 512, 512);
    // norm3(f) -> lnb (feat for ap1 AND pooling)
    ln_k<<<M / 4, 256, 0, stream>>>(fbB, n3_g, n3_b, lnb);
    // ap1+ap2 fused: aPart[row][nh] = tanh(lnb @ ap_w1 + b1) . ap_w2[half]
    gemm_k<6, false, false><<<nM * 2, 256, 0, stream>>>(lnb, 512, ap1T, ap_b1, nullptr, nullptr,
                                                        ap_w2, aPart, 256, 512);
    // softmax prep
    smprep_k<<<1, 1024, 0, stream>>>(aPart, M, sc);
    // pooled partials (feat = lnb, bf16)
    pool1_k<<<196, 256, 0, stream>>>(aPart, sc, lnb, partial);
    // final head
    final_k<<<1, 512, 0, stream>>>(partial, 196, fc2_w, fc2_b, (float*)d_out);
}